// Round 6
// baseline (144.952 us; speedup 1.0000x reference)
//
#include <hip/hip_runtime.h>
#include <hip/hip_bf16.h>
#include <math.h>

#define V 4096
#define E 8192
#define HV 256
#define HE 128
#define OUT_DIM 256
#define EPS 1e-6f

// mega2 block ranges (gemm1 + proj + zero)
#define G_GEMM1 256
#define G_PROJ  512
#define G_ZERO  64
#define G_TOTAL2 (G_GEMM1 + G_PROJ + G_ZERO)

typedef __attribute__((ext_vector_type(8))) short short8;
typedef __attribute__((ext_vector_type(4))) float f32x4;

__device__ __forceinline__ unsigned short f2bf(float f) {
    __hip_bfloat16 h = __float2bfloat16(f);
    return *(unsigned short*)&h;
}

__device__ __forceinline__ short8 cvt8(float4 a, float4 b) {
    short8 r;
    r[0] = f2bf(a.x); r[1] = f2bf(a.y); r[2] = f2bf(a.z); r[3] = f2bf(a.w);
    r[4] = f2bf(b.x); r[5] = f2bf(b.y); r[6] = f2bf(b.z); r[7] = f2bf(b.w);
    return r;
}

// ---------------------------------------------------------------------------
// Index scan as a streaming weighted reduction (branch-free hot loop):
//   idx[e] = sum_v (v+1) * m[v][e]  - 1
// Exactly one 1.0 per column -> sum is exact; unique row-chunk has nonzero
// partial -> single conditional writer, no atomics, no init needed.
// Grid: 2 matrices x 8 col-chunks x 64 row-chunks = 1024 blocks, 256 thr.
// Thread owns one float4-column (4 e-columns) over 64 rows: 64 x 16B loads,
// each consumed by one independent FMA -> deep software pipelining.
// ---------------------------------------------------------------------------
__global__ __launch_bounds__(256) void scan_kernel(const float4* __restrict__ vew1,
                                                   const float4* __restrict__ vew2,
                                                   int* __restrict__ iu,
                                                   int* __restrict__ iv) {
    const int b = blockIdx.x;
    const int mat = b >> 9;                 // 0: vew1, 1: vew2
    const int rem = b & 511;
    const int cchunk = rem & 7;             // 8 chunks of 256 f4cols
    const int rchunk = rem >> 3;            // 64 chunks of 64 rows
    const float4* m = mat ? vew2 : vew1;
    int* o = mat ? iv : iu;

    const int f4col = cchunk * 256 + threadIdx.x;   // 0..2047
    const int v0 = rchunk * 64;

    size_t off = (size_t)v0 * 2048 + f4col;         // E/4 = 2048 f4 per row
    float4 acc = {0.0f, 0.0f, 0.0f, 0.0f};
    #pragma unroll 8
    for (int r = 0; r < 64; ++r) {
        float4 x = m[off];
        float w = (float)(v0 + r + 1);
        acc.x += x.x * w; acc.y += x.y * w;
        acc.z += x.z * w; acc.w += x.w * w;
        off += 2048;
    }

    const int c4 = f4col * 4;
    if (acc.x != 0.0f) o[c4 + 0] = (int)acc.x - 1;
    if (acc.y != 0.0f) o[c4 + 1] = (int)acc.y - 1;
    if (acc.z != 0.0f) o[c4 + 2] = (int)acc.z - 1;
    if (acc.w != 0.0f) o[c4 + 3] = (int)acc.w - 1;
}

// ---------------------------------------------------------------------------
// bf16-MFMA GEMM body, f32 inputs converted during staging.
//   C[M,N] = act(Acat[M,Ktot] @ B + bias),  Acat = [A0 | A1] row stride KSEG.
//   B is f32 [Ktot][N] row-major (transposed into LDS during staging).
//   64x64 tile, 4 waves (2x2 of 32x32), BK=32, mfma_f32_16x16x32_bf16.
// ---------------------------------------------------------------------------
template <int ACT>
__device__ __forceinline__ void gemm_body(const float* __restrict__ A0,
                                          const float* __restrict__ A1,
                                          int KSEG, int NSEG,
                                          const float* __restrict__ B,
                                          const float* __restrict__ bias,
                                          float* __restrict__ Cout,
                                          int N, int bm, int bn) {
    __shared__ __align__(16) unsigned short As[64 * 40];   // [row][k] padded
    __shared__ __align__(16) unsigned short Bs[64 * 40];   // [col][k] padded
    const int tid  = threadIdx.x;
    const int lane = tid & 63;
    const int w    = tid >> 6;
    const int wm   = w >> 1, wn = w & 1;
    const int Ktot = KSEG * NSEG;

    const int sr  = tid >> 2;          // A staging row 0..63
    const int sc8 = (tid & 3) * 8;     // A staging k-offset {0,8,16,24}
    const int kb  = tid & 31;          // B staging k 0..31
    const int bc0 = (tid >> 5) * 8;    // B staging col group {0,8,...,56}
    const int fr  = lane & 15;
    const int kc  = (lane >> 4) * 8;

    f32x4 acc[2][2] = {};

    for (int k0 = 0; k0 < Ktot; k0 += 32) {
        const float* Asrc = (k0 >= KSEG) ? A1 : A0;
        int kk = (k0 >= KSEG) ? (k0 - KSEG) : k0;
        const float* ap = &Asrc[(size_t)(bm + sr) * KSEG + kk + sc8];
        float4 a0 = *(const float4*)ap;
        float4 a1 = *(const float4*)(ap + 4);
        const float* bp = &B[(size_t)(k0 + kb) * N + bn + bc0];
        float4 b0 = *(const float4*)bp;
        float4 b1 = *(const float4*)(bp + 4);
        *(short8*)&As[sr * 40 + sc8] = cvt8(a0, a1);
        unsigned short bw[8];
        bw[0] = f2bf(b0.x); bw[1] = f2bf(b0.y); bw[2] = f2bf(b0.z); bw[3] = f2bf(b0.w);
        bw[4] = f2bf(b1.x); bw[5] = f2bf(b1.y); bw[6] = f2bf(b1.z); bw[7] = f2bf(b1.w);
        #pragma unroll
        for (int j = 0; j < 8; ++j) Bs[(bc0 + j) * 40 + kb] = bw[j];
        __syncthreads();

        short8 bfr[2];
        bfr[0] = *(const short8*)&Bs[(wn * 32 + 0 * 16 + fr) * 40 + kc];
        bfr[1] = *(const short8*)&Bs[(wn * 32 + 1 * 16 + fr) * 40 + kc];
        #pragma unroll
        for (int ms = 0; ms < 2; ++ms) {
            short8 af = *(const short8*)&As[(wm * 32 + ms * 16 + fr) * 40 + kc];
            acc[ms][0] = __builtin_amdgcn_mfma_f32_16x16x32_bf16(af, bfr[0], acc[ms][0], 0, 0, 0);
            acc[ms][1] = __builtin_amdgcn_mfma_f32_16x16x32_bf16(af, bfr[1], acc[ms][1], 0, 0, 0);
        }
        __syncthreads();
    }

    #pragma unroll
    for (int ms = 0; ms < 2; ++ms) {
        #pragma unroll
        for (int ns = 0; ns < 2; ++ns) {
            int col = bn + wn * 32 + ns * 16 + fr;
            float bv = bias ? bias[col] : 0.0f;
            #pragma unroll
            for (int r = 0; r < 4; ++r) {
                int row = bm + wm * 32 + ms * 16 + ((lane >> 4) << 2) + r;
                float v = acc[ms][ns][r] + bv;
                if (ACT == 1) v = (v > 0.0f) ? v : 0.01f * v;   // leaky_relu
                Cout[(size_t)row * N + col] = v;
            }
        }
    }
}

template <int ACT>
__global__ __launch_bounds__(256) void gemm_kernel(const float* __restrict__ A0,
                                                   const float* __restrict__ A1,
                                                   int KSEG, int NSEG,
                                                   const float* __restrict__ B,
                                                   const float* __restrict__ bias,
                                                   float* __restrict__ C, int N) {
    gemm_body<ACT>(A0, A1, KSEG, NSEG, B, bias, C, N, blockIdx.y * 64, blockIdx.x * 64);
}

// ---------------------------------------------------------------------------
// mega2: gemm1 + proj + zero fused (independent DAG level)
// ---------------------------------------------------------------------------
__global__ __launch_bounds__(256) void mega2_kernel(
    const float* __restrict__ hv, const float* __restrict__ he,
    const float* __restrict__ watt,
    const float* __restrict__ wgcn, const float* __restrict__ bgcn,
    float* __restrict__ pu, float* __restrict__ pv, float* __restrict__ pe,
    float4* __restrict__ zbase, int zn4,
    float* __restrict__ X) {
    const int b = blockIdx.x;
    const int tid = threadIdx.x;

    if (b < G_GEMM1) {
        gemm_body<0>(hv, hv, HV, 1, wgcn, bgcn, X, HV, (b >> 2) * 64, (b & 3) * 64);
    } else if (b < G_GEMM1 + G_PROJ) {
        const int lane = tid & 63;
        for (int r = (b - G_GEMM1) * 4 + (tid >> 6); r < V + E; r += G_PROJ * 4) {
            if (r < V) {
                float4 x  = *(const float4*)(hv + (size_t)r * HV + lane * 4);
                float4 wu = *(const float4*)(watt + lane * 4);
                float4 wv = *(const float4*)(watt + HV + HE + lane * 4);
                float su = x.x * wu.x + x.y * wu.y + x.z * wu.z + x.w * wu.w;
                float sv = x.x * wv.x + x.y * wv.y + x.z * wv.z + x.w * wv.w;
                #pragma unroll
                for (int o = 32; o > 0; o >>= 1) {
                    su += __shfl_down(su, o);
                    sv += __shfl_down(sv, o);
                }
                if (lane == 0) { pu[r] = su; pv[r] = sv; }
            } else {
                int e = r - V;
                float2 x = *(const float2*)(he + (size_t)e * HE + lane * 2);
                float2 w = *(const float2*)(watt + HV + lane * 2);
                float s = x.x * w.x + x.y * w.y;
                #pragma unroll
                for (int o = 32; o > 0; o >>= 1) s += __shfl_down(s, o);
                if (lane == 0) pe[e] = s;
            }
        }
    } else {
        float4 z = {0.0f, 0.0f, 0.0f, 0.0f};
        for (int i = (b - G_GEMM1 - G_PROJ) * 256 + tid; i < zn4; i += G_ZERO * 256)
            zbase[i] = z;
    }
}

// ---------------------------------------------------------------------------
// Edge weights + degrees (atomics).
// ---------------------------------------------------------------------------
__global__ __launch_bounds__(256) void edge_kernel(const int* __restrict__ iu,
                                                   const int* __restrict__ iv,
                                                   const float* __restrict__ pu,
                                                   const float* __restrict__ pv,
                                                   const float* __restrict__ pe,
                                                   const float* __restrict__ batt,
                                                   float* __restrict__ ew,
                                                   float* __restrict__ dr,
                                                   float* __restrict__ dc) {
    int e2 = blockIdx.x * blockDim.x + threadIdx.x;
    if (e2 >= 2 * E) return;
    int e  = (e2 < E) ? e2 : e2 - E;
    int uu = (e2 < E) ? iu[e] : iv[e];
    int vv = (e2 < E) ? iv[e] : iu[e];
    float x = pu[uu] + pe[e] + pv[vv] + batt[0];
    float w = 1.0f / (1.0f + expf(-x));
    ew[e2] = w;
    atomicAdd(dr + uu, w);
    atomicAdd(dc + vv, w);
}

// ---------------------------------------------------------------------------
// Scatter: acc[uu][:] += ew[e2] * dc^{-1/2}[vv] * X[vv][:]
// ---------------------------------------------------------------------------
__global__ __launch_bounds__(64) void scatter_kernel(const int* __restrict__ iu,
                                                     const int* __restrict__ iv,
                                                     const float* __restrict__ ew,
                                                     const float* __restrict__ dc,
                                                     const float* __restrict__ X,
                                                     float* __restrict__ acc) {
    int e2 = blockIdx.x;
    int t  = threadIdx.x;
    int e  = (e2 < E) ? e2 : e2 - E;
    int uu = (e2 < E) ? iu[e] : iv[e];
    int vv = (e2 < E) ? iv[e] : iu[e];
    float coef = ew[e2] * rsqrtf(fmaxf(dc[vv], EPS));
    float4 x = *(const float4*)(X + (size_t)vv * HV + t * 4);
    float* dst = acc + (size_t)uu * HV + t * 4;
    atomicAdd(dst + 0, coef * x.x);
    atomicAdd(dst + 1, coef * x.y);
    atomicAdd(dst + 2, coef * x.z);
    atomicAdd(dst + 3, coef * x.w);
}

// ---------------------------------------------------------------------------
// Finish GCN (in place, f32): acc = tanh(d_r^{-1/2}[row] * acc)
// ---------------------------------------------------------------------------
__global__ __launch_bounds__(256) void finish_kernel(const float* __restrict__ dr,
                                                     float4* __restrict__ acc) {
    int i = blockIdx.x * 256 + threadIdx.x;      // grid exactly V*HV/4 threads
    int row = i >> 6;                            // 64 float4 per 256-float row
    float s = rsqrtf(fmaxf(dr[row], EPS));
    float4 x = acc[i];
    x.x = tanhf(s * x.x); x.y = tanhf(s * x.y);
    x.z = tanhf(s * x.z); x.w = tanhf(s * x.w);
    acc[i] = x;
}

// ---------------------------------------------------------------------------
extern "C" void kernel_launch(void* const* d_in, const int* in_sizes, int n_in,
                              void* d_out, int out_size, void* d_ws, size_t ws_size,
                              hipStream_t stream) {
    const float* hv   = (const float*)d_in[0];
    const float* he   = (const float*)d_in[1];
    const float* vew1 = (const float*)d_in[2];
    const float* vew2 = (const float*)d_in[3];
    const float* watt = (const float*)d_in[4];
    const float* batt = (const float*)d_in[5];
    const float* wgcn = (const float*)d_in[6];
    const float* bgcn = (const float*)d_in[7];
    const float* w1   = (const float*)d_in[8];
    const float* b1   = (const float*)d_in[9];
    const float* w2   = (const float*)d_in[10];
    const float* b2   = (const float*)d_in[11];
    float* out = (float*)d_out;

    // workspace (all f32 words)
    float* ws = (float*)d_ws;
    int*   iu  = (int*)ws;                       // E
    int*   iv  = (int*)(ws + E);                 // E
    float* pu  = ws + 2 * E;                     // V
    float* pv  = pu + V;                         // V
    float* pe  = pv + V;                         // E
    float* ew  = pe + E;                         // 2E
    float* dr  = ew + 2 * E;                     // V      (zeroed)
    float* dc  = dr + V;                         // V      (zeroed)
    float* acc = dc + V;                         // V*HV   (zeroed) -> hidden (in place)
    float* X   = acc + (size_t)V * HV;           // V*HV   (GCN linear out, later t)

    const int zn4 = (2 * V + V * HV) / 4;        // dr,dc,acc contiguous

    // level 1a: incidence scan as streaming reduction (isolated for counters)
    scan_kernel<<<1024, 256, 0, stream>>>((const float4*)vew1, (const float4*)vew2, iu, iv);

    // level 1b: gemm1 + proj + zero
    mega2_kernel<<<G_TOTAL2, 256, 0, stream>>>(hv, he, watt, wgcn, bgcn,
        pu, pv, pe, (float4*)dr, zn4, X);

    // level 2: edge weights + degrees
    edge_kernel<<<(2 * E + 255) / 256, 256, 0, stream>>>(iu, iv, pu, pv, pe, batt, ew, dr, dc);

    // level 3: scatter acc[uu] += ew * dc^{-1/2}[vv] * X[vv]
    scatter_kernel<<<2 * E, 64, 0, stream>>>(iu, iv, ew, dc, X, acc);

    // level 4: hidden = tanh(dr^{-1/2} * acc) in place
    finish_kernel<<<V * HV / 4 / 256, 256, 0, stream>>>(dr, (float4*)acc);

    // level 5: t = leaky_relu([hv | hidden] @ w1 + b1)  (K=512, two A segments)
    gemm_kernel<1><<<dim3(HV / 64, V / 64), 256, 0, stream>>>(hv, acc, HV, 2, w1, b1, X, HV);

    // level 6: out = t @ w2 + b2
    gemm_kernel<0><<<dim3(OUT_DIM / 64, V / 64), 256, 0, stream>>>(X, X, HV, 1, w2, b2, out, OUT_DIM);
}

// Round 8
// 139.349 us; speedup vs baseline: 1.0402x; 1.0402x over previous
//
#include <hip/hip_runtime.h>
#include <hip/hip_bf16.h>
#include <math.h>

#define V 4096
#define E 8192
#define HV 256
#define HE 128
#define OUT_DIM 256
#define EPS 1e-6f

// mega-kernel block ranges (level-1 of the dependency DAG)
#define G_GEMM1 256
#define G_PROJ  512
#define G_ZERO  64
#define G_IDX   8192   /* 4096 per incidence matrix, one-shot blocks */
#define G_TOTAL (G_GEMM1 + G_PROJ + G_ZERO + G_IDX)

typedef __attribute__((ext_vector_type(8))) short short8;
typedef __attribute__((ext_vector_type(4))) float f32x4;

__device__ __forceinline__ unsigned short f2bf(float f) {
    __hip_bfloat16 h = __float2bfloat16(f);
    return *(unsigned short*)&h;
}

__device__ __forceinline__ short8 cvt8(float4 a, float4 b) {
    short8 r;
    r[0] = f2bf(a.x); r[1] = f2bf(a.y); r[2] = f2bf(a.z); r[3] = f2bf(a.w);
    r[4] = f2bf(b.x); r[5] = f2bf(b.y); r[6] = f2bf(b.z); r[7] = f2bf(b.w);
    return r;
}

// ---------------------------------------------------------------------------
// bf16-MFMA GEMM body, f32 inputs converted during staging.
//   C[M,N] = act(Acat[M,Ktot] @ B + bias),  Acat = [A0 | A1] row stride KSEG.
//   B is f32 [Ktot][N] row-major (transposed into LDS during staging).
//   64x64 tile, 4 waves (2x2 of 32x32), BK=32, mfma_f32_16x16x32_bf16.
// ---------------------------------------------------------------------------
template <int ACT>
__device__ __forceinline__ void gemm_body(const float* __restrict__ A0,
                                          const float* __restrict__ A1,
                                          int KSEG, int NSEG,
                                          const float* __restrict__ B,
                                          const float* __restrict__ bias,
                                          float* __restrict__ Cout,
                                          int N, int bm, int bn) {
    __shared__ __align__(16) unsigned short As[64 * 40];   // [row][k] padded
    __shared__ __align__(16) unsigned short Bs[64 * 40];   // [col][k] padded
    const int tid  = threadIdx.x;
    const int lane = tid & 63;
    const int w    = tid >> 6;
    const int wm   = w >> 1, wn = w & 1;
    const int Ktot = KSEG * NSEG;

    const int sr  = tid >> 2;          // A staging row 0..63
    const int sc8 = (tid & 3) * 8;     // A staging k-offset {0,8,16,24}
    const int kb  = tid & 31;          // B staging k 0..31
    const int bc0 = (tid >> 5) * 8;    // B staging col group {0,8,...,56}
    const int fr  = lane & 15;
    const int kc  = (lane >> 4) * 8;

    f32x4 acc[2][2] = {};

    for (int k0 = 0; k0 < Ktot; k0 += 32) {
        const float* Asrc = (k0 >= KSEG) ? A1 : A0;
        int kk = (k0 >= KSEG) ? (k0 - KSEG) : k0;
        const float* ap = &Asrc[(size_t)(bm + sr) * KSEG + kk + sc8];
        float4 a0 = *(const float4*)ap;
        float4 a1 = *(const float4*)(ap + 4);
        const float* bp = &B[(size_t)(k0 + kb) * N + bn + bc0];
        float4 b0 = *(const float4*)bp;
        float4 b1 = *(const float4*)(bp + 4);
        *(short8*)&As[sr * 40 + sc8] = cvt8(a0, a1);
        unsigned short bw[8];
        bw[0] = f2bf(b0.x); bw[1] = f2bf(b0.y); bw[2] = f2bf(b0.z); bw[3] = f2bf(b0.w);
        bw[4] = f2bf(b1.x); bw[5] = f2bf(b1.y); bw[6] = f2bf(b1.z); bw[7] = f2bf(b1.w);
        #pragma unroll
        for (int j = 0; j < 8; ++j) Bs[(bc0 + j) * 40 + kb] = bw[j];
        __syncthreads();

        short8 bfr[2];
        bfr[0] = *(const short8*)&Bs[(wn * 32 + 0 * 16 + fr) * 40 + kc];
        bfr[1] = *(const short8*)&Bs[(wn * 32 + 1 * 16 + fr) * 40 + kc];
        #pragma unroll
        for (int ms = 0; ms < 2; ++ms) {
            short8 af = *(const short8*)&As[(wm * 32 + ms * 16 + fr) * 40 + kc];
            acc[ms][0] = __builtin_amdgcn_mfma_f32_16x16x32_bf16(af, bfr[0], acc[ms][0], 0, 0, 0);
            acc[ms][1] = __builtin_amdgcn_mfma_f32_16x16x32_bf16(af, bfr[1], acc[ms][1], 0, 0, 0);
        }
        __syncthreads();
    }

    #pragma unroll
    for (int ms = 0; ms < 2; ++ms) {
        #pragma unroll
        for (int ns = 0; ns < 2; ++ns) {
            int col = bn + wn * 32 + ns * 16 + fr;
            float bv = bias ? bias[col] : 0.0f;
            #pragma unroll
            for (int r = 0; r < 4; ++r) {
                int row = bm + wm * 32 + ms * 16 + ((lane >> 4) << 2) + r;
                float v = acc[ms][ns][r] + bv;
                if (ACT == 1) v = (v > 0.0f) ? v : 0.01f * v;   // leaky_relu
                Cout[(size_t)row * N + col] = v;
            }
        }
    }
}

template <int ACT>
__global__ __launch_bounds__(256) void gemm_kernel(const float* __restrict__ A0,
                                                   const float* __restrict__ A1,
                                                   int KSEG, int NSEG,
                                                   const float* __restrict__ B,
                                                   const float* __restrict__ bias,
                                                   float* __restrict__ C, int N) {
    gemm_body<ACT>(A0, A1, KSEG, NSEG, B, bias, C, N, blockIdx.y * 64, blockIdx.x * 64);
}

// ---------------------------------------------------------------------------
// Mega-kernel: level-1 of the DAG fused (scan co-resident with the rest).
//   [0, G_GEMM1)   : X = hv @ w_gcn + b_gcn   (MFMA)
//   [+, G_PROJ)    : attention projections pu/pv/pe
//   [+, G_ZERO)    : zero dr/dc/acc
//   [+, G_IDX)     : one-hot index extraction, 268 MB scan.
//                    NONTEMPORAL loads (nt): bypass L1/L2 allocation --
//                    testing the per-CU miss-path ceiling theory.
// ---------------------------------------------------------------------------
__global__ __launch_bounds__(256) void mega_kernel(
    const float* __restrict__ hv, const float* __restrict__ he,
    const f32x4* __restrict__ vew1, const f32x4* __restrict__ vew2,
    const float* __restrict__ watt,
    const float* __restrict__ wgcn, const float* __restrict__ bgcn,
    int* __restrict__ iu, int* __restrict__ iv,
    float* __restrict__ pu, float* __restrict__ pv, float* __restrict__ pe,
    float4* __restrict__ zbase, int zn4,
    float* __restrict__ X) {
    const int b = blockIdx.x;
    const int tid = threadIdx.x;

    if (b < G_GEMM1) {
        gemm_body<0>(hv, hv, HV, 1, wgcn, bgcn, X, HV, (b >> 2) * 64, (b & 3) * 64);
    } else if (b < G_GEMM1 + G_PROJ) {
        const int lane = tid & 63;
        for (int r = (b - G_GEMM1) * 4 + (tid >> 6); r < V + E; r += G_PROJ * 4) {
            if (r < V) {
                float4 x  = *(const float4*)(hv + (size_t)r * HV + lane * 4);
                float4 wu = *(const float4*)(watt + lane * 4);
                float4 wv = *(const float4*)(watt + HV + HE + lane * 4);
                float su = x.x * wu.x + x.y * wu.y + x.z * wu.z + x.w * wu.w;
                float sv = x.x * wv.x + x.y * wv.y + x.z * wv.z + x.w * wv.w;
                #pragma unroll
                for (int o = 32; o > 0; o >>= 1) {
                    su += __shfl_down(su, o);
                    sv += __shfl_down(sv, o);
                }
                if (lane == 0) { pu[r] = su; pv[r] = sv; }
            } else {
                int e = r - V;
                float2 x = *(const float2*)(he + (size_t)e * HE + lane * 2);
                float2 w = *(const float2*)(watt + HV + lane * 2);
                float s = x.x * w.x + x.y * w.y;
                #pragma unroll
                for (int o = 32; o > 0; o >>= 1) s += __shfl_down(s, o);
                if (lane == 0) pe[e] = s;
            }
        }
    } else if (b < G_GEMM1 + G_PROJ + G_ZERO) {
        float4 z = {0.0f, 0.0f, 0.0f, 0.0f};
        for (int i = (b - G_GEMM1 - G_PROJ) * 256 + tid; i < zn4; i += G_ZERO * 256)
            zbase[i] = z;
    } else {
        int ib = b - (G_GEMM1 + G_PROJ + G_ZERO);
        const f32x4* m = (ib < G_IDX / 2) ? vew1 : vew2;
        int* o = (ib < G_IDX / 2) ? iu : iv;
        ib &= (G_IDX / 2 - 1);
        size_t base = (size_t)ib * 2048 + tid;

        // nontemporal streaming loads (no L1/L2 allocation)
        f32x4 x[8];
        #pragma unroll
        for (int it = 0; it < 8; ++it)
            x[it] = __builtin_nontemporal_load(&m[base + (size_t)it * 256]);

        #pragma unroll
        for (int it = 0; it < 8; ++it) {
            f32x4 v4 = x[it];
            if (v4[0] + v4[1] + v4[2] + v4[3] > 0.5f) {
                size_t i = base + (size_t)it * 256;
                int v  = (int)(i >> 11);            // EQ = E/4 = 2048
                int c4 = ((int)i & 2047) << 2;
                if (v4[0] > 0.5f) o[c4 + 0] = v;
                if (v4[1] > 0.5f) o[c4 + 1] = v;
                if (v4[2] > 0.5f) o[c4 + 2] = v;
                if (v4[3] > 0.5f) o[c4 + 3] = v;
            }
        }
    }
}

// ---------------------------------------------------------------------------
// Edge weights + degrees (atomics).
// ---------------------------------------------------------------------------
__global__ __launch_bounds__(256) void edge_kernel(const int* __restrict__ iu,
                                                   const int* __restrict__ iv,
                                                   const float* __restrict__ pu,
                                                   const float* __restrict__ pv,
                                                   const float* __restrict__ pe,
                                                   const float* __restrict__ batt,
                                                   float* __restrict__ ew,
                                                   float* __restrict__ dr,
                                                   float* __restrict__ dc) {
    int e2 = blockIdx.x * blockDim.x + threadIdx.x;
    if (e2 >= 2 * E) return;
    int e  = (e2 < E) ? e2 : e2 - E;
    int uu = (e2 < E) ? iu[e] : iv[e];
    int vv = (e2 < E) ? iv[e] : iu[e];
    float x = pu[uu] + pe[e] + pv[vv] + batt[0];
    float w = 1.0f / (1.0f + expf(-x));
    ew[e2] = w;
    atomicAdd(dr + uu, w);
    atomicAdd(dc + vv, w);
}

// ---------------------------------------------------------------------------
// Scatter: acc[uu][:] += ew[e2] * dc^{-1/2}[vv] * X[vv][:]
// ---------------------------------------------------------------------------
__global__ __launch_bounds__(64) void scatter_kernel(const int* __restrict__ iu,
                                                     const int* __restrict__ iv,
                                                     const float* __restrict__ ew,
                                                     const float* __restrict__ dc,
                                                     const float* __restrict__ X,
                                                     float* __restrict__ acc) {
    int e2 = blockIdx.x;
    int t  = threadIdx.x;
    int e  = (e2 < E) ? e2 : e2 - E;
    int uu = (e2 < E) ? iu[e] : iv[e];
    int vv = (e2 < E) ? iv[e] : iu[e];
    float coef = ew[e2] * rsqrtf(fmaxf(dc[vv], EPS));
    float4 x = *(const float4*)(X + (size_t)vv * HV + t * 4);
    float* dst = acc + (size_t)uu * HV + t * 4;
    atomicAdd(dst + 0, coef * x.x);
    atomicAdd(dst + 1, coef * x.y);
    atomicAdd(dst + 2, coef * x.z);
    atomicAdd(dst + 3, coef * x.w);
}

// ---------------------------------------------------------------------------
// Finish GCN (in place, f32): acc = tanh(d_r^{-1/2}[row] * acc)
// ---------------------------------------------------------------------------
__global__ __launch_bounds__(256) void finish_kernel(const float* __restrict__ dr,
                                                     float4* __restrict__ acc) {
    int i = blockIdx.x * 256 + threadIdx.x;      // grid exactly V*HV/4 threads
    int row = i >> 6;                            // 64 float4 per 256-float row
    float s = rsqrtf(fmaxf(dr[row], EPS));
    float4 x = acc[i];
    x.x = tanhf(s * x.x); x.y = tanhf(s * x.y);
    x.z = tanhf(s * x.z); x.w = tanhf(s * x.w);
    acc[i] = x;
}

// ---------------------------------------------------------------------------
extern "C" void kernel_launch(void* const* d_in, const int* in_sizes, int n_in,
                              void* d_out, int out_size, void* d_ws, size_t ws_size,
                              hipStream_t stream) {
    const float* hv   = (const float*)d_in[0];
    const float* he   = (const float*)d_in[1];
    const float* vew1 = (const float*)d_in[2];
    const float* vew2 = (const float*)d_in[3];
    const float* watt = (const float*)d_in[4];
    const float* batt = (const float*)d_in[5];
    const float* wgcn = (const float*)d_in[6];
    const float* bgcn = (const float*)d_in[7];
    const float* w1   = (const float*)d_in[8];
    const float* b1   = (const float*)d_in[9];
    const float* w2   = (const float*)d_in[10];
    const float* b2   = (const float*)d_in[11];
    float* out = (float*)d_out;

    // workspace (all f32 words)
    float* ws = (float*)d_ws;
    int*   iu  = (int*)ws;                       // E
    int*   iv  = (int*)(ws + E);                 // E
    float* pu  = ws + 2 * E;                     // V
    float* pv  = pu + V;                         // V
    float* pe  = pv + V;                         // E
    float* ew  = pe + E;                         // 2E
    float* dr  = ew + 2 * E;                     // V      (zeroed)
    float* dc  = dr + V;                         // V      (zeroed)
    float* acc = dc + V;                         // V*HV   (zeroed) -> hidden (in place)
    float* X   = acc + (size_t)V * HV;           // V*HV   (GCN linear out, later t)

    const int zn4 = (2 * V + V * HV) / 4;        // dr,dc,acc contiguous

    // level 1: idx scans (nt loads) + proj + gemm1 + zero, co-scheduled
    mega_kernel<<<G_TOTAL, 256, 0, stream>>>(hv, he, (const f32x4*)vew1,
        (const f32x4*)vew2, watt, wgcn, bgcn, iu, iv, pu, pv, pe,
        (float4*)dr, zn4, X);

    // level 2: edge weights + degrees
    edge_kernel<<<(2 * E + 255) / 256, 256, 0, stream>>>(iu, iv, pu, pv, pe, batt, ew, dr, dc);

    // level 3: scatter acc[uu] += ew * dc^{-1/2}[vv] * X[vv]
    scatter_kernel<<<2 * E, 64, 0, stream>>>(iu, iv, ew, dc, X, acc);

    // level 4: hidden = tanh(dr^{-1/2} * acc) in place
    finish_kernel<<<V * HV / 4 / 256, 256, 0, stream>>>(dr, (float4*)acc);

    // level 5: t = leaky_relu([hv | hidden] @ w1 + b1)  (K=512, two A segments)
    gemm_kernel<1><<<dim3(HV / 64, V / 64), 256, 0, stream>>>(hv, acc, HV, 2, w1, b1, X, HV);

    // level 6: out = t @ w2 + b2
    gemm_kernel<0><<<dim3(OUT_DIM / 64, V / 64), 256, 0, stream>>>(X, X, HV, 1, w2, b2, out, OUT_DIM);
}

// Round 9
// 135.749 us; speedup vs baseline: 1.0678x; 1.0265x over previous
//
#include <hip/hip_runtime.h>
#include <hip/hip_bf16.h>
#include <math.h>

#define V 4096
#define E 8192
#define HV 256
#define HE 128
#define OUT_DIM 256
#define EPS 1e-6f

// mega-kernel block ranges (level-1 of the dependency DAG)
#define G_GEMM1 256
#define G_PROJ  512
#define G_ZERO  64
#define G_IDX   8192   /* 4096 per incidence matrix, one-shot blocks */
#define G_TOTAL (G_GEMM1 + G_PROJ + G_ZERO + G_IDX)

typedef __attribute__((ext_vector_type(8))) short short8;
typedef __attribute__((ext_vector_type(4))) float f32x4;

__device__ __forceinline__ unsigned short f2bf(float f) {
    __hip_bfloat16 h = __float2bfloat16(f);
    return *(unsigned short*)&h;
}

__device__ __forceinline__ short8 cvt8(float4 a, float4 b) {
    short8 r;
    r[0] = f2bf(a.x); r[1] = f2bf(a.y); r[2] = f2bf(a.z); r[3] = f2bf(a.w);
    r[4] = f2bf(b.x); r[5] = f2bf(b.y); r[6] = f2bf(b.z); r[7] = f2bf(b.w);
    return r;
}

// ---------------------------------------------------------------------------
// bf16-MFMA GEMM body, f32 inputs converted during staging.
//   C[M,N] = act(Acat[M,Ktot] @ B + bias),  Acat = [A0 | A1] row stride KSEG.
//   B is f32 [Ktot][N] row-major (transposed into LDS during staging).
//   64x64 tile, 4 waves (2x2 of 32x32), BK=32, mfma_f32_16x16x32_bf16.
// ---------------------------------------------------------------------------
template <int ACT>
__device__ __forceinline__ void gemm_body(const float* __restrict__ A0,
                                          const float* __restrict__ A1,
                                          int KSEG, int NSEG,
                                          const float* __restrict__ B,
                                          const float* __restrict__ bias,
                                          float* __restrict__ Cout,
                                          int N, int bm, int bn) {
    __shared__ __align__(16) unsigned short As[64 * 40];   // [row][k] padded
    __shared__ __align__(16) unsigned short Bs[64 * 40];   // [col][k] padded
    const int tid  = threadIdx.x;
    const int lane = tid & 63;
    const int w    = tid >> 6;
    const int wm   = w >> 1, wn = w & 1;
    const int Ktot = KSEG * NSEG;

    const int sr  = tid >> 2;          // A staging row 0..63
    const int sc8 = (tid & 3) * 8;     // A staging k-offset {0,8,16,24}
    const int kb  = tid & 31;          // B staging k 0..31
    const int bc0 = (tid >> 5) * 8;    // B staging col group {0,8,...,56}
    const int fr  = lane & 15;
    const int kc  = (lane >> 4) * 8;

    f32x4 acc[2][2] = {};

    for (int k0 = 0; k0 < Ktot; k0 += 32) {
        const float* Asrc = (k0 >= KSEG) ? A1 : A0;
        int kk = (k0 >= KSEG) ? (k0 - KSEG) : k0;
        const float* ap = &Asrc[(size_t)(bm + sr) * KSEG + kk + sc8];
        float4 a0 = *(const float4*)ap;
        float4 a1 = *(const float4*)(ap + 4);
        const float* bp = &B[(size_t)(k0 + kb) * N + bn + bc0];
        float4 b0 = *(const float4*)bp;
        float4 b1 = *(const float4*)(bp + 4);
        *(short8*)&As[sr * 40 + sc8] = cvt8(a0, a1);
        unsigned short bw[8];
        bw[0] = f2bf(b0.x); bw[1] = f2bf(b0.y); bw[2] = f2bf(b0.z); bw[3] = f2bf(b0.w);
        bw[4] = f2bf(b1.x); bw[5] = f2bf(b1.y); bw[6] = f2bf(b1.z); bw[7] = f2bf(b1.w);
        #pragma unroll
        for (int j = 0; j < 8; ++j) Bs[(bc0 + j) * 40 + kb] = bw[j];
        __syncthreads();

        short8 bfr[2];
        bfr[0] = *(const short8*)&Bs[(wn * 32 + 0 * 16 + fr) * 40 + kc];
        bfr[1] = *(const short8*)&Bs[(wn * 32 + 1 * 16 + fr) * 40 + kc];
        #pragma unroll
        for (int ms = 0; ms < 2; ++ms) {
            short8 af = *(const short8*)&As[(wm * 32 + ms * 16 + fr) * 40 + kc];
            acc[ms][0] = __builtin_amdgcn_mfma_f32_16x16x32_bf16(af, bfr[0], acc[ms][0], 0, 0, 0);
            acc[ms][1] = __builtin_amdgcn_mfma_f32_16x16x32_bf16(af, bfr[1], acc[ms][1], 0, 0, 0);
        }
        __syncthreads();
    }

    #pragma unroll
    for (int ms = 0; ms < 2; ++ms) {
        #pragma unroll
        for (int ns = 0; ns < 2; ++ns) {
            int col = bn + wn * 32 + ns * 16 + fr;
            float bv = bias ? bias[col] : 0.0f;
            #pragma unroll
            for (int r = 0; r < 4; ++r) {
                int row = bm + wm * 32 + ms * 16 + ((lane >> 4) << 2) + r;
                float v = acc[ms][ns][r] + bv;
                if (ACT == 1) v = (v > 0.0f) ? v : 0.01f * v;   // leaky_relu
                Cout[(size_t)row * N + col] = v;
            }
        }
    }
}

template <int ACT>
__global__ __launch_bounds__(256) void gemm_kernel(const float* __restrict__ A0,
                                                   const float* __restrict__ A1,
                                                   int KSEG, int NSEG,
                                                   const float* __restrict__ B,
                                                   const float* __restrict__ bias,
                                                   float* __restrict__ C, int N) {
    gemm_body<ACT>(A0, A1, KSEG, NSEG, B, bias, C, N, blockIdx.y * 64, blockIdx.x * 64);
}

// ---------------------------------------------------------------------------
// Mega-kernel: level-1 of the DAG fused.
//   [0, G_GEMM1)   : X = hv @ w_gcn + b_gcn   (MFMA)
//   [+, G_PROJ)    : attention projections pu/pv/pe
//   [+, G_ZERO)    : zero dr/dc/acc
//   [+, G_IDX)     : one-hot index extraction, 268 MB scan.
//                    8 loads batched + sched_barrier(0) fence so the
//                    scheduler CANNOT sink them -- 8 KB in flight per wave.
//                    (Verify: mega VGPR_Count must rise to >= 56.)
// ---------------------------------------------------------------------------
__global__ __launch_bounds__(256) void mega_kernel(
    const float* __restrict__ hv, const float* __restrict__ he,
    const f32x4* __restrict__ vew1, const f32x4* __restrict__ vew2,
    const float* __restrict__ watt,
    const float* __restrict__ wgcn, const float* __restrict__ bgcn,
    int* __restrict__ iu, int* __restrict__ iv,
    float* __restrict__ pu, float* __restrict__ pv, float* __restrict__ pe,
    float4* __restrict__ zbase, int zn4,
    float* __restrict__ X) {
    const int b = blockIdx.x;
    const int tid = threadIdx.x;

    if (b < G_GEMM1) {
        gemm_body<0>(hv, hv, HV, 1, wgcn, bgcn, X, HV, (b >> 2) * 64, (b & 3) * 64);
    } else if (b < G_GEMM1 + G_PROJ) {
        const int lane = tid & 63;
        for (int r = (b - G_GEMM1) * 4 + (tid >> 6); r < V + E; r += G_PROJ * 4) {
            if (r < V) {
                float4 x  = *(const float4*)(hv + (size_t)r * HV + lane * 4);
                float4 wu = *(const float4*)(watt + lane * 4);
                float4 wv = *(const float4*)(watt + HV + HE + lane * 4);
                float su = x.x * wu.x + x.y * wu.y + x.z * wu.z + x.w * wu.w;
                float sv = x.x * wv.x + x.y * wv.y + x.z * wv.z + x.w * wv.w;
                #pragma unroll
                for (int o = 32; o > 0; o >>= 1) {
                    su += __shfl_down(su, o);
                    sv += __shfl_down(sv, o);
                }
                if (lane == 0) { pu[r] = su; pv[r] = sv; }
            } else {
                int e = r - V;
                float2 x = *(const float2*)(he + (size_t)e * HE + lane * 2);
                float2 w = *(const float2*)(watt + HV + lane * 2);
                float s = x.x * w.x + x.y * w.y;
                #pragma unroll
                for (int o = 32; o > 0; o >>= 1) s += __shfl_down(s, o);
                if (lane == 0) pe[e] = s;
            }
        }
    } else if (b < G_GEMM1 + G_PROJ + G_ZERO) {
        float4 z = {0.0f, 0.0f, 0.0f, 0.0f};
        for (int i = (b - G_GEMM1 - G_PROJ) * 256 + tid; i < zn4; i += G_ZERO * 256)
            zbase[i] = z;
    } else {
        int ib = b - (G_GEMM1 + G_PROJ + G_ZERO);
        const f32x4* m = (ib < G_IDX / 2) ? vew1 : vew2;
        int* o = (ib < G_IDX / 2) ? iu : iv;
        ib &= (G_IDX / 2 - 1);
        size_t base = (size_t)ib * 2048 + tid;

        // phase 1: 8 independent loads, all issued before the fence
        f32x4 x[8];
        #pragma unroll
        for (int it = 0; it < 8; ++it)
            x[it] = m[base + (size_t)it * 256];
        __builtin_amdgcn_sched_barrier(0);   // nothing may cross: loads stay batched

        // phase 2: test + rare scatter writes
        #pragma unroll
        for (int it = 0; it < 8; ++it) {
            f32x4 v4 = x[it];
            if (v4[0] + v4[1] + v4[2] + v4[3] > 0.5f) {
                size_t i = base + (size_t)it * 256;
                int v  = (int)(i >> 11);            // EQ = E/4 = 2048
                int c4 = ((int)i & 2047) << 2;
                if (v4[0] > 0.5f) o[c4 + 0] = v;
                if (v4[1] > 0.5f) o[c4 + 1] = v;
                if (v4[2] > 0.5f) o[c4 + 2] = v;
                if (v4[3] > 0.5f) o[c4 + 3] = v;
            }
        }
    }
}

// ---------------------------------------------------------------------------
// Edge weights + degrees (atomics).
// ---------------------------------------------------------------------------
__global__ __launch_bounds__(256) void edge_kernel(const int* __restrict__ iu,
                                                   const int* __restrict__ iv,
                                                   const float* __restrict__ pu,
                                                   const float* __restrict__ pv,
                                                   const float* __restrict__ pe,
                                                   const float* __restrict__ batt,
                                                   float* __restrict__ ew,
                                                   float* __restrict__ dr,
                                                   float* __restrict__ dc) {
    int e2 = blockIdx.x * blockDim.x + threadIdx.x;
    if (e2 >= 2 * E) return;
    int e  = (e2 < E) ? e2 : e2 - E;
    int uu = (e2 < E) ? iu[e] : iv[e];
    int vv = (e2 < E) ? iv[e] : iu[e];
    float x = pu[uu] + pe[e] + pv[vv] + batt[0];
    float w = 1.0f / (1.0f + expf(-x));
    ew[e2] = w;
    atomicAdd(dr + uu, w);
    atomicAdd(dc + vv, w);
}

// ---------------------------------------------------------------------------
// Scatter: acc[uu][:] += ew[e2] * dc^{-1/2}[vv] * X[vv][:]
// ---------------------------------------------------------------------------
__global__ __launch_bounds__(64) void scatter_kernel(const int* __restrict__ iu,
                                                     const int* __restrict__ iv,
                                                     const float* __restrict__ ew,
                                                     const float* __restrict__ dc,
                                                     const float* __restrict__ X,
                                                     float* __restrict__ acc) {
    int e2 = blockIdx.x;
    int t  = threadIdx.x;
    int e  = (e2 < E) ? e2 : e2 - E;
    int uu = (e2 < E) ? iu[e] : iv[e];
    int vv = (e2 < E) ? iv[e] : iu[e];
    float coef = ew[e2] * rsqrtf(fmaxf(dc[vv], EPS));
    float4 x = *(const float4*)(X + (size_t)vv * HV + t * 4);
    float* dst = acc + (size_t)uu * HV + t * 4;
    atomicAdd(dst + 0, coef * x.x);
    atomicAdd(dst + 1, coef * x.y);
    atomicAdd(dst + 2, coef * x.z);
    atomicAdd(dst + 3, coef * x.w);
}

// ---------------------------------------------------------------------------
// Finish GCN (in place, f32): acc = tanh(d_r^{-1/2}[row] * acc)
// ---------------------------------------------------------------------------
__global__ __launch_bounds__(256) void finish_kernel(const float* __restrict__ dr,
                                                     float4* __restrict__ acc) {
    int i = blockIdx.x * 256 + threadIdx.x;      // grid exactly V*HV/4 threads
    int row = i >> 6;                            // 64 float4 per 256-float row
    float s = rsqrtf(fmaxf(dr[row], EPS));
    float4 x = acc[i];
    x.x = tanhf(s * x.x); x.y = tanhf(s * x.y);
    x.z = tanhf(s * x.z); x.w = tanhf(s * x.w);
    acc[i] = x;
}

// ---------------------------------------------------------------------------
extern "C" void kernel_launch(void* const* d_in, const int* in_sizes, int n_in,
                              void* d_out, int out_size, void* d_ws, size_t ws_size,
                              hipStream_t stream) {
    const float* hv   = (const float*)d_in[0];
    const float* he   = (const float*)d_in[1];
    const float* vew1 = (const float*)d_in[2];
    const float* vew2 = (const float*)d_in[3];
    const float* watt = (const float*)d_in[4];
    const float* batt = (const float*)d_in[5];
    const float* wgcn = (const float*)d_in[6];
    const float* bgcn = (const float*)d_in[7];
    const float* w1   = (const float*)d_in[8];
    const float* b1   = (const float*)d_in[9];
    const float* w2   = (const float*)d_in[10];
    const float* b2   = (const float*)d_in[11];
    float* out = (float*)d_out;

    // workspace (all f32 words)
    float* ws = (float*)d_ws;
    int*   iu  = (int*)ws;                       // E
    int*   iv  = (int*)(ws + E);                 // E
    float* pu  = ws + 2 * E;                     // V
    float* pv  = pu + V;                         // V
    float* pe  = pv + V;                         // E
    float* ew  = pe + E;                         // 2E
    float* dr  = ew + 2 * E;                     // V      (zeroed)
    float* dc  = dr + V;                         // V      (zeroed)
    float* acc = dc + V;                         // V*HV   (zeroed) -> hidden (in place)
    float* X   = acc + (size_t)V * HV;           // V*HV   (GCN linear out, later t)

    const int zn4 = (2 * V + V * HV) / 4;        // dr,dc,acc contiguous

    // level 1: idx scans (batched loads + fence) + proj + gemm1 + zero
    mega_kernel<<<G_TOTAL, 256, 0, stream>>>(hv, he, (const f32x4*)vew1,
        (const f32x4*)vew2, watt, wgcn, bgcn, iu, iv, pu, pv, pe,
        (float4*)dr, zn4, X);

    // level 2: edge weights + degrees
    edge_kernel<<<(2 * E + 255) / 256, 256, 0, stream>>>(iu, iv, pu, pv, pe, batt, ew, dr, dc);

    // level 3: scatter acc[uu] += ew * dc^{-1/2}[vv] * X[vv]
    scatter_kernel<<<2 * E, 64, 0, stream>>>(iu, iv, ew, dc, X, acc);

    // level 4: hidden = tanh(dr^{-1/2} * acc) in place
    finish_kernel<<<V * HV / 4 / 256, 256, 0, stream>>>(dr, (float4*)acc);

    // level 5: t = leaky_relu([hv | hidden] @ w1 + b1)  (K=512, two A segments)
    gemm_kernel<1><<<dim3(HV / 64, V / 64), 256, 0, stream>>>(hv, acc, HV, 2, w1, b1, X, HV);

    // level 6: out = t @ w2 + b2
    gemm_kernel<0><<<dim3(OUT_DIM / 64, V / 64), 256, 0, stream>>>(X, X, HV, 1, w2, b2, out, OUT_DIM);
}

// Round 10
// 135.393 us; speedup vs baseline: 1.0706x; 1.0026x over previous
//
#include <hip/hip_runtime.h>
#include <hip/hip_bf16.h>
#include <math.h>

#define V 4096
#define E 8192
#define HV 256
#define HE 128
#define OUT_DIM 256
#define EPS 1e-6f

// mega-kernel block ranges (level-1 of the dependency DAG)
#define G_GEMM1 256
#define G_PROJ  512
#define G_ZERO  64
#define G_IDX   8192   /* 4096 per incidence matrix, one-shot blocks */
#define G_TOTAL (G_GEMM1 + G_PROJ + G_ZERO + G_IDX)

typedef __attribute__((ext_vector_type(8))) short short8;
typedef __attribute__((ext_vector_type(4))) float f32x4;

__device__ __forceinline__ unsigned short f2bf(float f) {
    __hip_bfloat16 h = __float2bfloat16(f);
    return *(unsigned short*)&h;
}

__device__ __forceinline__ short8 cvt8(float4 a, float4 b) {
    short8 r;
    r[0] = f2bf(a.x); r[1] = f2bf(a.y); r[2] = f2bf(a.z); r[3] = f2bf(a.w);
    r[4] = f2bf(b.x); r[5] = f2bf(b.y); r[6] = f2bf(b.z); r[7] = f2bf(b.w);
    return r;
}

// ---------------------------------------------------------------------------
// bf16-MFMA GEMM body, f32 inputs converted during staging.
//   C[M,N] = act(Acat[M,Ktot] @ B + bias),  Acat = [A0 | A1] row stride KSEG.
//   B is f32 [Ktot][N] row-major (transposed into LDS during staging).
//   64x64 tile, 4 waves (2x2 of 32x32), BK=32, mfma_f32_16x16x32_bf16.
// ---------------------------------------------------------------------------
template <int ACT>
__device__ __forceinline__ void gemm_body(const float* __restrict__ A0,
                                          const float* __restrict__ A1,
                                          int KSEG, int NSEG,
                                          const float* __restrict__ B,
                                          const float* __restrict__ bias,
                                          float* __restrict__ Cout,
                                          int N, int bm, int bn) {
    __shared__ __align__(16) unsigned short As[64 * 40];   // [row][k] padded
    __shared__ __align__(16) unsigned short Bs[64 * 40];   // [col][k] padded
    const int tid  = threadIdx.x;
    const int lane = tid & 63;
    const int w    = tid >> 6;
    const int wm   = w >> 1, wn = w & 1;
    const int Ktot = KSEG * NSEG;

    const int sr  = tid >> 2;          // A staging row 0..63
    const int sc8 = (tid & 3) * 8;     // A staging k-offset {0,8,16,24}
    const int kb  = tid & 31;          // B staging k 0..31
    const int bc0 = (tid >> 5) * 8;    // B staging col group {0,8,...,56}
    const int fr  = lane & 15;
    const int kc  = (lane >> 4) * 8;

    f32x4 acc[2][2] = {};

    for (int k0 = 0; k0 < Ktot; k0 += 32) {
        const float* Asrc = (k0 >= KSEG) ? A1 : A0;
        int kk = (k0 >= KSEG) ? (k0 - KSEG) : k0;
        const float* ap = &Asrc[(size_t)(bm + sr) * KSEG + kk + sc8];
        float4 a0 = *(const float4*)ap;
        float4 a1 = *(const float4*)(ap + 4);
        const float* bp = &B[(size_t)(k0 + kb) * N + bn + bc0];
        float4 b0 = *(const float4*)bp;
        float4 b1 = *(const float4*)(bp + 4);
        *(short8*)&As[sr * 40 + sc8] = cvt8(a0, a1);
        unsigned short bw[8];
        bw[0] = f2bf(b0.x); bw[1] = f2bf(b0.y); bw[2] = f2bf(b0.z); bw[3] = f2bf(b0.w);
        bw[4] = f2bf(b1.x); bw[5] = f2bf(b1.y); bw[6] = f2bf(b1.z); bw[7] = f2bf(b1.w);
        #pragma unroll
        for (int j = 0; j < 8; ++j) Bs[(bc0 + j) * 40 + kb] = bw[j];
        __syncthreads();

        short8 bfr[2];
        bfr[0] = *(const short8*)&Bs[(wn * 32 + 0 * 16 + fr) * 40 + kc];
        bfr[1] = *(const short8*)&Bs[(wn * 32 + 1 * 16 + fr) * 40 + kc];
        #pragma unroll
        for (int ms = 0; ms < 2; ++ms) {
            short8 af = *(const short8*)&As[(wm * 32 + ms * 16 + fr) * 40 + kc];
            acc[ms][0] = __builtin_amdgcn_mfma_f32_16x16x32_bf16(af, bfr[0], acc[ms][0], 0, 0, 0);
            acc[ms][1] = __builtin_amdgcn_mfma_f32_16x16x32_bf16(af, bfr[1], acc[ms][1], 0, 0, 0);
        }
        __syncthreads();
    }

    #pragma unroll
    for (int ms = 0; ms < 2; ++ms) {
        #pragma unroll
        for (int ns = 0; ns < 2; ++ns) {
            int col = bn + wn * 32 + ns * 16 + fr;
            float bv = bias ? bias[col] : 0.0f;
            #pragma unroll
            for (int r = 0; r < 4; ++r) {
                int row = bm + wm * 32 + ms * 16 + ((lane >> 4) << 2) + r;
                float v = acc[ms][ns][r] + bv;
                if (ACT == 1) v = (v > 0.0f) ? v : 0.01f * v;   // leaky_relu
                Cout[(size_t)row * N + col] = v;
            }
        }
    }
}

template <int ACT>
__global__ __launch_bounds__(256) void gemm_kernel(const float* __restrict__ A0,
                                                   const float* __restrict__ A1,
                                                   int KSEG, int NSEG,
                                                   const float* __restrict__ B,
                                                   const float* __restrict__ bias,
                                                   float* __restrict__ C, int N) {
    gemm_body<ACT>(A0, A1, KSEG, NSEG, B, bias, C, N, blockIdx.y * 64, blockIdx.x * 64);
}

// ---------------------------------------------------------------------------
// Mega-kernel: level-1 of the DAG fused.
//   [0, G_GEMM1)   : X = hv @ w_gcn + b_gcn   (MFMA)
//   [+, G_PROJ)    : attention projections pu/pv/pe
//   [+, G_ZERO)    : zero dr/dc/acc
//   [+, G_IDX)     : one-hot index extraction, 268 MB scan.
//                    DEFINITIVE MLP test: 8 global_load_dwordx4 inside ONE
//                    asm block + s_waitcnt vmcnt(0) -- compiler cannot sink
//                    or split them. 8 KB in flight per wave, guaranteed.
//                    (Verify: mega VGPR_Count must rise to >= 48.)
// ---------------------------------------------------------------------------
__global__ __launch_bounds__(256) void mega_kernel(
    const float* __restrict__ hv, const float* __restrict__ he,
    const f32x4* __restrict__ vew1, const f32x4* __restrict__ vew2,
    const float* __restrict__ watt,
    const float* __restrict__ wgcn, const float* __restrict__ bgcn,
    int* __restrict__ iu, int* __restrict__ iv,
    float* __restrict__ pu, float* __restrict__ pv, float* __restrict__ pe,
    float4* __restrict__ zbase, int zn4,
    float* __restrict__ X) {
    const int b = blockIdx.x;
    const int tid = threadIdx.x;

    if (b < G_GEMM1) {
        gemm_body<0>(hv, hv, HV, 1, wgcn, bgcn, X, HV, (b >> 2) * 64, (b & 3) * 64);
    } else if (b < G_GEMM1 + G_PROJ) {
        const int lane = tid & 63;
        for (int r = (b - G_GEMM1) * 4 + (tid >> 6); r < V + E; r += G_PROJ * 4) {
            if (r < V) {
                float4 x  = *(const float4*)(hv + (size_t)r * HV + lane * 4);
                float4 wu = *(const float4*)(watt + lane * 4);
                float4 wv = *(const float4*)(watt + HV + HE + lane * 4);
                float su = x.x * wu.x + x.y * wu.y + x.z * wu.z + x.w * wu.w;
                float sv = x.x * wv.x + x.y * wv.y + x.z * wv.z + x.w * wv.w;
                #pragma unroll
                for (int o = 32; o > 0; o >>= 1) {
                    su += __shfl_down(su, o);
                    sv += __shfl_down(sv, o);
                }
                if (lane == 0) { pu[r] = su; pv[r] = sv; }
            } else {
                int e = r - V;
                float2 x = *(const float2*)(he + (size_t)e * HE + lane * 2);
                float2 w = *(const float2*)(watt + HV + lane * 2);
                float s = x.x * w.x + x.y * w.y;
                #pragma unroll
                for (int o = 32; o > 0; o >>= 1) s += __shfl_down(s, o);
                if (lane == 0) pe[e] = s;
            }
        }
    } else if (b < G_GEMM1 + G_PROJ + G_ZERO) {
        float4 z = {0.0f, 0.0f, 0.0f, 0.0f};
        for (int i = (b - G_GEMM1 - G_PROJ) * 256 + tid; i < zn4; i += G_ZERO * 256)
            zbase[i] = z;
    } else {
        int ib = b - (G_GEMM1 + G_PROJ + G_ZERO);
        const f32x4* m = (ib < G_IDX / 2) ? vew1 : vew2;
        int* o = (ib < G_IDX / 2) ? iu : iv;
        ib &= (G_IDX / 2 - 1);
        size_t base = (size_t)ib * 2048 + tid;

        // phase 1: 8 loads in ONE asm block -- guaranteed 8 in flight.
        const f32x4* p0 = m + base;
        const f32x4* p1 = m + base + 1 * 256;
        const f32x4* p2 = m + base + 2 * 256;
        const f32x4* p3 = m + base + 3 * 256;
        const f32x4* p4 = m + base + 4 * 256;
        const f32x4* p5 = m + base + 5 * 256;
        const f32x4* p6 = m + base + 6 * 256;
        const f32x4* p7 = m + base + 7 * 256;
        f32x4 x0, x1, x2, x3, x4, x5, x6, x7;
        asm volatile(
            "global_load_dwordx4 %0, %8, off\n\t"
            "global_load_dwordx4 %1, %9, off\n\t"
            "global_load_dwordx4 %2, %10, off\n\t"
            "global_load_dwordx4 %3, %11, off\n\t"
            "global_load_dwordx4 %4, %12, off\n\t"
            "global_load_dwordx4 %5, %13, off\n\t"
            "global_load_dwordx4 %6, %14, off\n\t"
            "global_load_dwordx4 %7, %15, off\n\t"
            "s_waitcnt vmcnt(0)"
            : "=&v"(x0), "=&v"(x1), "=&v"(x2), "=&v"(x3),
              "=&v"(x4), "=&v"(x5), "=&v"(x6), "=&v"(x7)
            : "v"(p0), "v"(p1), "v"(p2), "v"(p3),
              "v"(p4), "v"(p5), "v"(p6), "v"(p7)
            : "memory");
        __builtin_amdgcn_sched_barrier(0);

        // phase 2: test + rare scatter writes
        f32x4 xs[8] = {x0, x1, x2, x3, x4, x5, x6, x7};
        #pragma unroll
        for (int it = 0; it < 8; ++it) {
            f32x4 v4 = xs[it];
            if (v4[0] + v4[1] + v4[2] + v4[3] > 0.5f) {
                size_t i = base + (size_t)it * 256;
                int v  = (int)(i >> 11);            // EQ = E/4 = 2048
                int c4 = ((int)i & 2047) << 2;
                if (v4[0] > 0.5f) o[c4 + 0] = v;
                if (v4[1] > 0.5f) o[c4 + 1] = v;
                if (v4[2] > 0.5f) o[c4 + 2] = v;
                if (v4[3] > 0.5f) o[c4 + 3] = v;
            }
        }
    }
}

// ---------------------------------------------------------------------------
// Edge weights + degrees (atomics).
// ---------------------------------------------------------------------------
__global__ __launch_bounds__(256) void edge_kernel(const int* __restrict__ iu,
                                                   const int* __restrict__ iv,
                                                   const float* __restrict__ pu,
                                                   const float* __restrict__ pv,
                                                   const float* __restrict__ pe,
                                                   const float* __restrict__ batt,
                                                   float* __restrict__ ew,
                                                   float* __restrict__ dr,
                                                   float* __restrict__ dc) {
    int e2 = blockIdx.x * blockDim.x + threadIdx.x;
    if (e2 >= 2 * E) return;
    int e  = (e2 < E) ? e2 : e2 - E;
    int uu = (e2 < E) ? iu[e] : iv[e];
    int vv = (e2 < E) ? iv[e] : iu[e];
    float x = pu[uu] + pe[e] + pv[vv] + batt[0];
    float w = 1.0f / (1.0f + expf(-x));
    ew[e2] = w;
    atomicAdd(dr + uu, w);
    atomicAdd(dc + vv, w);
}

// ---------------------------------------------------------------------------
// Scatter: acc[uu][:] += ew[e2] * dc^{-1/2}[vv] * X[vv][:]
// ---------------------------------------------------------------------------
__global__ __launch_bounds__(64) void scatter_kernel(const int* __restrict__ iu,
                                                     const int* __restrict__ iv,
                                                     const float* __restrict__ ew,
                                                     const float* __restrict__ dc,
                                                     const float* __restrict__ X,
                                                     float* __restrict__ acc) {
    int e2 = blockIdx.x;
    int t  = threadIdx.x;
    int e  = (e2 < E) ? e2 : e2 - E;
    int uu = (e2 < E) ? iu[e] : iv[e];
    int vv = (e2 < E) ? iv[e] : iu[e];
    float coef = ew[e2] * rsqrtf(fmaxf(dc[vv], EPS));
    float4 x = *(const float4*)(X + (size_t)vv * HV + t * 4);
    float* dst = acc + (size_t)uu * HV + t * 4;
    atomicAdd(dst + 0, coef * x.x);
    atomicAdd(dst + 1, coef * x.y);
    atomicAdd(dst + 2, coef * x.z);
    atomicAdd(dst + 3, coef * x.w);
}

// ---------------------------------------------------------------------------
// Finish GCN (in place, f32): acc = tanh(d_r^{-1/2}[row] * acc)
// ---------------------------------------------------------------------------
__global__ __launch_bounds__(256) void finish_kernel(const float* __restrict__ dr,
                                                     float4* __restrict__ acc) {
    int i = blockIdx.x * 256 + threadIdx.x;      // grid exactly V*HV/4 threads
    int row = i >> 6;                            // 64 float4 per 256-float row
    float s = rsqrtf(fmaxf(dr[row], EPS));
    float4 x = acc[i];
    x.x = tanhf(s * x.x); x.y = tanhf(s * x.y);
    x.z = tanhf(s * x.z); x.w = tanhf(s * x.w);
    acc[i] = x;
}

// ---------------------------------------------------------------------------
extern "C" void kernel_launch(void* const* d_in, const int* in_sizes, int n_in,
                              void* d_out, int out_size, void* d_ws, size_t ws_size,
                              hipStream_t stream) {
    const float* hv   = (const float*)d_in[0];
    const float* he   = (const float*)d_in[1];
    const float* vew1 = (const float*)d_in[2];
    const float* vew2 = (const float*)d_in[3];
    const float* watt = (const float*)d_in[4];
    const float* batt = (const float*)d_in[5];
    const float* wgcn = (const float*)d_in[6];
    const float* bgcn = (const float*)d_in[7];
    const float* w1   = (const float*)d_in[8];
    const float* b1   = (const float*)d_in[9];
    const float* w2   = (const float*)d_in[10];
    const float* b2   = (const float*)d_in[11];
    float* out = (float*)d_out;

    // workspace (all f32 words)
    float* ws = (float*)d_ws;
    int*   iu  = (int*)ws;                       // E
    int*   iv  = (int*)(ws + E);                 // E
    float* pu  = ws + 2 * E;                     // V
    float* pv  = pu + V;                         // V
    float* pe  = pv + V;                         // E
    float* ew  = pe + E;                         // 2E
    float* dr  = ew + 2 * E;                     // V      (zeroed)
    float* dc  = dr + V;                         // V      (zeroed)
    float* acc = dc + V;                         // V*HV   (zeroed) -> hidden (in place)
    float* X   = acc + (size_t)V * HV;           // V*HV   (GCN linear out, later t)

    const int zn4 = (2 * V + V * HV) / 4;        // dr,dc,acc contiguous

    // level 1: idx scans (asm-batched loads) + proj + gemm1 + zero
    mega_kernel<<<G_TOTAL, 256, 0, stream>>>(hv, he, (const f32x4*)vew1,
        (const f32x4*)vew2, watt, wgcn, bgcn, iu, iv, pu, pv, pe,
        (float4*)dr, zn4, X);

    // level 2: edge weights + degrees
    edge_kernel<<<(2 * E + 255) / 256, 256, 0, stream>>>(iu, iv, pu, pv, pe, batt, ew, dr, dc);

    // level 3: scatter acc[uu] += ew * dc^{-1/2}[vv] * X[vv]
    scatter_kernel<<<2 * E, 64, 0, stream>>>(iu, iv, ew, dc, X, acc);

    // level 4: hidden = tanh(dr^{-1/2} * acc) in place
    finish_kernel<<<V * HV / 4 / 256, 256, 0, stream>>>(dr, (float4*)acc);

    // level 5: t = leaky_relu([hv | hidden] @ w1 + b1)  (K=512, two A segments)
    gemm_kernel<1><<<dim3(HV / 64, V / 64), 256, 0, stream>>>(hv, acc, HV, 2, w1, b1, X, HV);

    // level 6: out = t @ w2 + b2
    gemm_kernel<0><<<dim3(OUT_DIM / 64, V / 64), 256, 0, stream>>>(X, X, HV, 1, w2, b2, out, OUT_DIM);
}